// Round 6
// baseline (243.151 us; speedup 1.0000x reference)
//
#include <hip/hip_runtime.h>

typedef __attribute__((ext_vector_type(4))) float f32x4;
typedef __attribute__((ext_vector_type(8))) short short8;
typedef __attribute__((ext_vector_type(4))) unsigned short us4;
typedef unsigned short u16;
typedef unsigned int u32;
typedef _Float16 f16;
typedef __attribute__((ext_vector_type(8))) f16 f16x8;

#define B_   16
#define N_   2048
#define C_   256
#define CIN  131
#define COUT 128
#define L2E  1.44269504088896f

__device__ __forceinline__ u16 f2bf(float x) {
    u32 u = __float_as_uint(x);
    u32 r = (u + 0x7fffu + ((u >> 16) & 1u)) >> 16;
    return (u16)r;
}
__device__ __forceinline__ float bf2f(u16 h) {
    return __uint_as_float(((u32)h) << 16);
}
__device__ __forceinline__ u16 f2h(float x) {
    union { f16 h; u16 u; } c; c.h = (f16)x; return c.u;
}
__device__ __forceinline__ float h2f(u16 u) {
    union { u16 u; f16 h; } c; c.u = u; return (float)c.h;
}

__device__ __forceinline__ f32x4 mfma16(short8 a, short8 b, f32x4 c) {
    return __builtin_amdgcn_mfma_f32_16x16x32_bf16(a, b, c, 0, 0, 0);
}
__device__ __forceinline__ f32x4 mfma16h(f16x8 a, f16x8 b, f32x4 c) {
    return __builtin_amdgcn_mfma_f32_16x16x32_f16(a, b, c, 0, 0, 0);
}

typedef __attribute__((address_space(1))) const unsigned int gu32;
typedef __attribute__((address_space(3))) unsigned int lu32;
// dst must be wave-uniform; HW writes dst + lane*16B. src is per-lane.
__device__ __forceinline__ void gl_lds16(const u16* g, u16* l) {
    __builtin_amdgcn_global_load_lds((gu32*)g, (lu32*)l, 16, 0, 0);
}

// raw barrier without the __syncthreads() implicit vmcnt(0) drain
#define RAW_BARRIER() do { asm volatile("" ::: "memory"); \
    __builtin_amdgcn_s_barrier(); \
    asm volatile("" ::: "memory"); } while (0)

// ---------------------------------------------------------------------------
// Kernel 1: weight prep (unchanged).
// ---------------------------------------------------------------------------
__global__ __launch_bounds__(256) void w_prep(
    const float* __restrict__ Wq, const float* __restrict__ Wk,
    const float* __restrict__ Wv, const float* __restrict__ Wf,
    const float* __restrict__ bnq, const float* __restrict__ bnk,
    const float* __restrict__ bnv, const float* __restrict__ bnf,
    u16* __restrict__ wAh, u16* __restrict__ wAl,
    u16* __restrict__ wfh, u16* __restrict__ wfl,
    float* __restrict__ sqkv, float* __restrict__ tqkv,
    float* __restrict__ sf, float* __restrict__ tf)
{
    int t = threadIdx.x, l = t & 63;
    int g = blockIdx.x * 4 + (t >> 6);
    if (g < 240) {
        int m = g / 80, rem = g % 80, og = rem / 5, cc = rem % 5;
        const float* W = (m == 0) ? Wq : (m == 1) ? Wk : Wv;
        int o = og * 16 + (l & 15);
        size_t base = ((size_t)g * 64 + l) * 8;
        #pragma unroll
        for (int j = 0; j < 8; ++j) {
            int k = cc * 32 + (l >> 4) * 8 + j;
            float f = (k < CIN) ? W[o * CIN + k] : 0.f;
            u16 h = f2bf(f);
            wAh[base + j] = h;
            wAl[base + j] = f2bf(f - bf2f(h));
        }
    } else if (g < 304) {
        int u = g - 240;
        int o = (u >> 3) * 16 + (l & 15);
        int c0 = (u & 7) * 32 + (l >> 4) * 8;
        size_t base = ((size_t)u * 64 + l) * 8;
        #pragma unroll
        for (int j = 0; j < 8; ++j) {
            float f = Wf[o * 256 + c0 + j];
            u16 h = f2h(f);
            wfh[base + j] = h;
            wfl[base + j] = f2h(f - h2f(h));
        }
    }
    if (blockIdx.x == 0) {
        if (t < 256) {
            #pragma unroll
            for (int m = 0; m < 3; ++m) {
                const float* bn = (m == 0) ? bnq : (m == 1) ? bnk : bnv;
                float s = bn[t] * rsqrtf(bn[768 + t] + 1e-5f);
                sqkv[m * 256 + t] = s;
                tqkv[m * 256 + t] = bn[256 + t] - bn[512 + t] * s;
            }
        }
        if (t < 128) {
            float s = bnf[t] * rsqrtf(bnf[384 + t] + 1e-5f);
            sf[t] = s;
            tf[t] = bnf[128 + t] - bnf[256 + t] * s;
        }
    }
}

// ---------------------------------------------------------------------------
// Kernel 2: QKV projection via MFMA hi/lo bf16 (unchanged from R5).
// ---------------------------------------------------------------------------
__global__ __launch_bounds__(256) void qkv_proj(
    const float* __restrict__ x,
    const u16* __restrict__ wAh, const u16* __restrict__ wAl,
    const float* __restrict__ sqkv, const float* __restrict__ tqkv,
    u16* __restrict__ qh, u16* __restrict__ ql,
    u16* __restrict__ kh, u16* __restrict__ kl, u16* __restrict__ vt)
{
    __shared__ __align__(16) float xs[64][164];

    int bid = blockIdx.x;
    int m  = bid >> 9;
    int r9 = bid & 511;
    int b = r9 >> 5, nt = r9 & 31;
    int t = threadIdx.x;
    int w = t >> 6, l = t & 63;
    int n0 = nt * 64;

    {
        int nb = (t & 15) * 4;
        for (int k = (t >> 4); k < CIN; k += 16) {
            f32x4 v = *(const f32x4*)(x + ((size_t)b * CIN + k) * N_ + n0 + nb);
            xs[nb + 0][k] = v[0]; xs[nb + 1][k] = v[1];
            xs[nb + 2][k] = v[2]; xs[nb + 3][k] = v[3];
        }
        for (int idx = t; idx < 64 * 29; idx += 256) {
            int n = idx / 29, k = CIN + idx % 29;
            xs[n][k] = 0.f;
        }
    }
    __syncthreads();

    f32x4 acc[4][4];
    #pragma unroll
    for (int og = 0; og < 4; ++og)
        #pragma unroll
        for (int njg = 0; njg < 4; ++njg) acc[og][njg] = (f32x4){0.f, 0.f, 0.f, 0.f};

    for (int cc = 0; cc < 5; ++cc) {
        short8 xbh[4], xbl[4];
        #pragma unroll
        for (int njg = 0; njg < 4; ++njg) {
            int n = njg * 16 + (l & 15);
            int k0 = cc * 32 + (l >> 4) * 8;
            f32x4 u0 = *(const f32x4*)&xs[n][k0];
            f32x4 u1 = *(const f32x4*)&xs[n][k0 + 4];
            u16 hh[8], ll[8];
            #pragma unroll
            for (int jj = 0; jj < 4; ++jj) {
                hh[jj] = f2bf(u0[jj]);     ll[jj] = f2bf(u0[jj] - bf2f(hh[jj]));
                hh[4 + jj] = f2bf(u1[jj]); ll[4 + jj] = f2bf(u1[jj] - bf2f(hh[4 + jj]));
            }
            short8 vh_, vl_;
            #pragma unroll
            for (int jj = 0; jj < 8; ++jj) { vh_[jj] = (short)hh[jj]; vl_[jj] = (short)ll[jj]; }
            xbh[njg] = vh_; xbl[njg] = vl_;
        }
        #pragma unroll
        for (int og = 0; og < 4; ++og) {
            size_t base = (((size_t)(m * 16 + w * 4 + og) * 5 + cc) * 64 + l) * 8;
            short8 ah  = *(const short8*)(wAh + base);
            short8 al4 = *(const short8*)(wAl + base);
            #pragma unroll
            for (int njg = 0; njg < 4; ++njg) {
                acc[og][njg] = mfma16(ah,  xbh[njg], acc[og][njg]);
                acc[og][njg] = mfma16(ah,  xbl[njg], acc[og][njg]);
                acc[og][njg] = mfma16(al4, xbh[njg], acc[og][njg]);
            }
        }
    }

    #pragma unroll
    for (int og = 0; og < 4; ++og) {
        int cb = (w * 4 + og) * 16 + (l >> 4) * 4;
        f32x4 sv = *(const f32x4*)(sqkv + m * 256 + cb);
        f32x4 tv = *(const f32x4*)(tqkv + m * 256 + cb);
        #pragma unroll
        for (int njg = 0; njg < 4; ++njg) {
            int n = n0 + njg * 16 + (l & 15);
            float z[4];
            #pragma unroll
            for (int r = 0; r < 4; ++r)
                z[r] = fmaxf(fmaf(acc[og][njg][r], sv[r], tv[r]), 0.f);
            size_t base = ((((size_t)b * 128 + (n >> 4)) * 8 + (cb >> 5)) * 64
                           + ((cb >> 3) & 3) * 16 + (n & 15)) * 8 + (cb & 7);
            if (m < 2) {
                if (m == 1)
                    base = (((((size_t)b * 64 + (n >> 5)) * 2 + ((n >> 4) & 1)) * 8 + (cb >> 5)) * 64
                            + ((cb >> 3) & 3) * 16 + (n & 15)) * 8 + (cb & 7);
                u16 h0 = f2bf(z[0]), h1 = f2bf(z[1]), h2 = f2bf(z[2]), h3 = f2bf(z[3]);
                us4 hi4 = { h0, h1, h2, h3 };
                us4 lo4 = { f2bf(z[0] - bf2f(h0)), f2bf(z[1] - bf2f(h1)),
                            f2bf(z[2] - bf2f(h2)), f2bf(z[3] - bf2f(h3)) };
                *(us4*)((m ? kh : qh) + base) = hi4;
                *(us4*)((m ? kl : ql) + base) = lo4;
            } else {
                us4 v0 = { f2h(z[0]), f2h(z[1]), f2h(z[2]), f2h(z[3]) };
                *(us4*)(vt + base) = v0;
            }
        }
    }
}

// ---------------------------------------------------------------------------
// Kernel 2b: VW = V^T · Wf  (unchanged from R5).
// ---------------------------------------------------------------------------
__global__ __launch_bounds__(256) void vw_proj(
    const u16* __restrict__ vt,
    const u16* __restrict__ wfh, const u16* __restrict__ wfl,
    u16* __restrict__ vw)
{
    int bid = blockIdx.x;
    int b = bid >> 4, mt = bid & 15;
    int t = threadIdx.x, w = t >> 6, l = t & 63;

    f32x4 acc[2][8];
    #pragma unroll
    for (int oi = 0; oi < 2; ++oi)
        #pragma unroll
        for (int mg = 0; mg < 8; ++mg) acc[oi][mg] = (f32x4){0.f, 0.f, 0.f, 0.f};

    for (int cc = 0; cc < 8; ++cc) {
        f16x8 vtf[8];
        #pragma unroll
        for (int mg = 0; mg < 8; ++mg)
            vtf[mg] = *(const f16x8*)(vt + ((((size_t)b * 128 + mt * 8 + mg) * 8 + cc) * 64 + l) * 8);
        #pragma unroll
        for (int oi = 0; oi < 2; ++oi) {
            int og = w * 2 + oi;
            f16x8 bh = *(const f16x8*)(wfh + (((size_t)og * 8 + cc) * 64 + l) * 8);
            f16x8 bl = *(const f16x8*)(wfl + (((size_t)og * 8 + cc) * 64 + l) * 8);
            #pragma unroll
            for (int mg = 0; mg < 8; ++mg) {
                acc[oi][mg] = mfma16h(vtf[mg], bh, acc[oi][mg]);
                acc[oi][mg] = mfma16h(vtf[mg], bl, acc[oi][mg]);
            }
        }
    }

    #pragma unroll
    for (int oi = 0; oi < 2; ++oi) {
        int og = w * 2 + oi;
        int ol = l & 15;
        #pragma unroll
        for (int mg = 0; mg < 8; ++mg) {
            #pragma unroll
            for (int r = 0; r < 4; ++r) {
                int mm = mt * 128 + mg * 16 + (l >> 4) * 4 + r;
                size_t idx = ((((size_t)b * 64 + (mm >> 5)) * 8 + og) * 64
                              + ((mm >> 3) & 3) * 16 + ol) * 8 + (mm & 7);
                vw[idx] = f2h(acc[oi][mg][r]);
            }
        }
    }
}

// ---------------------------------------------------------------------------
// Kernel 3: flash attention, T4 discipline: raw s_barrier + counted vmcnt.
// Per wave per iter: 8 K loads then 2 VW loads (order matters for vmcnt).
//   loop invariant at iter top: K(mc) fully staged (prev iter's vmcnt(2)+bar).
//   barrier A (post-QK): K readers done -> safe to overwrite K buf.
//   vmcnt(10) before PV: prev iter's VW(mc) landed (oldest-first drain).
//   vmcnt(2) + barrier B: this iter's K(mc+1) landed; 2 VW stay in flight.
// LDS (52KB u16): KH @0, KL @8192, VW0 @16384, VW1 @20480, PH @24576+w*512
// ---------------------------------------------------------------------------
__global__ __launch_bounds__(256, 3) void attn_fwd(
    const u16* __restrict__ qh, const u16* __restrict__ ql,
    const u16* __restrict__ kh, const u16* __restrict__ kl,
    const u16* __restrict__ vw,
    const float* __restrict__ sf, const float* __restrict__ tf,
    float* __restrict__ out)
{
    __shared__ __align__(16) u16 smem[26624];

    int bid = blockIdx.x;
    int swz = (bid & 7) * 64 + (bid >> 3);   // XCD-chunked swizzle (bijective, 512 blocks)
    int b   = swz >> 5;
    int nt  = swz & 31;
    int tid = threadIdx.x;
    int w = tid >> 6, l = tid & 63;
    int ng = nt * 4 + w;

    const u16* khb = kh + (size_t)b * 64 * 8192;
    const u16* klb = kl + (size_t)b * 64 * 8192;
    const u16* vwb = vw + (size_t)b * 64 * 4096;

    auto stageK = [&](int mc) {               // 32 rows (KH16+KL16), 8 per wave
        size_t mo = (size_t)mc * 8192;
        #pragma unroll
        for (int i = 0; i < 8; ++i) {
            int r = w * 8 + i;
            const u16* g; int dst;
            if (r < 16) { g = khb + mo + r * 512;        dst = r * 512; }
            else        { g = klb + mo + (r - 16) * 512; dst = 8192 + (r - 16) * 512; }
            gl_lds16(g + l * 8, &smem[dst]);
        }
    };
    auto stageVW = [&](int mc, int vbase) {   // 8 rows of 1KB, 2 per wave
        size_t mo = (size_t)mc * 4096;
        #pragma unroll
        for (int i = 0; i < 2; ++i) {
            int r = w * 2 + i;
            gl_lds16(vwb + mo + r * 512 + l * 8, &smem[vbase + r * 512]);
        }
    };

    // Q fragments in registers (hi/lo), 8 K-chunks of 32
    short8 qfh[8], qfl[8];
    {
        const u16* qbh = qh + (((size_t)b * 128 + ng) * 8 * 64 + l) * 8;
        const u16* qbl = ql + (((size_t)b * 128 + ng) * 8 * 64 + l) * 8;
        #pragma unroll
        for (int cc = 0; cc < 8; ++cc) {
            qfh[cc] = *(const short8*)(qbh + cc * 512);
            qfl[cc] = *(const short8*)(qbl + cc * 512);
        }
    }

    f32x4 O[8];
    #pragma unroll
    for (int og = 0; og < 8; ++og) O[og] = (f32x4){0.f, 0.f, 0.f, 0.f};
    float mrow[4] = {-1e30f, -1e30f, -1e30f, -1e30f};
    float lrow[4] = {0.f, 0.f, 0.f, 0.f};

    // prologue: tile 0 staged and drained
    stageK(0);
    stageVW(0, 16384);
    asm volatile("s_waitcnt vmcnt(0)" ::: "memory");
    __syncthreads();

    u16* PH = &smem[24576 + w * 512];

    for (int mc = 0; mc < 64; ++mc) {
        // ---- S = Q^T K (3-pass hi/lo bf16); K(mc) ready by invariant ----
        f32x4 s0v = (f32x4){0.f, 0.f, 0.f, 0.f};
        f32x4 s1v = (f32x4){0.f, 0.f, 0.f, 0.f};
        const short8* KH8 = (const short8*)&smem[0];
        const short8* KL8 = (const short8*)&smem[8192];
        __builtin_amdgcn_s_setprio(1);
        #pragma unroll
        for (int cc = 0; cc < 8; ++cc) {
            short8 k0h = KH8[cc * 64 + l];
            short8 k0l = KL8[cc * 64 + l];
            short8 k1h = KH8[(8 + cc) * 64 + l];
            short8 k1l = KL8[(8 + cc) * 64 + l];
            s0v = mfma16(qfh[cc], k0h, s0v);
            s0v = mfma16(qfh[cc], k0l, s0v);
            s0v = mfma16(qfl[cc], k0h, s0v);
            s1v = mfma16(qfh[cc], k1h, s1v);
            s1v = mfma16(qfh[cc], k1l, s1v);
            s1v = mfma16(qfl[cc], k1h, s1v);
        }
        __builtin_amdgcn_s_setprio(0);

        RAW_BARRIER();                        // barrier A: K readers done (no drain)

        if (mc < 63) {
            stageK(mc + 1);                   // 8 loads (issued first)
            stageVW(mc + 1, 16384 + ((mc + 1) & 1) * 4096);   // then 2
        }

        // ---- online softmax (defer-rescale, THR=8) ----
        float tm[4];
        #pragma unroll
        for (int r = 0; r < 4; ++r) tm[r] = fmaxf(s0v[r], s1v[r]);
        #pragma unroll
        for (int off = 1; off < 16; off <<= 1) {
            #pragma unroll
            for (int r = 0; r < 4; ++r) tm[r] = fmaxf(tm[r], __shfl_xor(tm[r], off));
        }
        bool need = false;
        #pragma unroll
        for (int r = 0; r < 4; ++r) need = need || (tm[r] > mrow[r] + 8.f);
        if (__any(need)) {
            #pragma unroll
            for (int r = 0; r < 4; ++r) {
                float mn = fmaxf(mrow[r], tm[r]);
                float al = exp2f((mrow[r] - mn) * L2E);
                mrow[r] = mn;
                lrow[r] *= al;
                #pragma unroll
                for (int og = 0; og < 8; ++og) O[og][r] *= al;
            }
        }
        u16 p0u[4], p1u[4];
        float rs[4];
        #pragma unroll
        for (int r = 0; r < 4; ++r) {
            p0u[r] = f2h(exp2f((s0v[r] - mrow[r]) * L2E));
            p1u[r] = f2h(exp2f((s1v[r] - mrow[r]) * L2E));
            rs[r] = h2f(p0u[r]) + h2f(p1u[r]);   // denominator matches fp16 numerator mass
        }
        #pragma unroll
        for (int off = 1; off < 16; off <<= 1) {
            #pragma unroll
            for (int r = 0; r < 4; ++r) rs[r] += __shfl_xor(rs[r], off);
        }
        #pragma unroll
        for (int r = 0; r < 4; ++r) lrow[r] += rs[r];

        // P (fp16) -> per-wave LDS bounce into A-frag layout
        {
            int colm = l & 15, rowb = (l >> 4) * 4;
            #pragma unroll
            for (int mf = 0; mf < 2; ++mf) {
                int mloc = mf * 16 + colm;
                int lp = (mloc >> 3) * 16, j = mloc & 7;
                #pragma unroll
                for (int r = 0; r < 4; ++r)
                    PH[(lp + rowb + r) * 8 + j] = mf ? p1u[r] : p0u[r];
            }
        }

        // wait for VW(mc): it is the oldest in-flight pair (10 newer allowed)
        if (mc < 63) { asm volatile("s_waitcnt vmcnt(10)" ::: "memory"); }
        else         { asm volatile("s_waitcnt vmcnt(0)"  ::: "memory"); }

        // ---- O += P · VW (fp16, 8 MFMA) ----
        f16x8 pa = *(const f16x8*)(PH + l * 8);
        const f16x8* VW8 = (const f16x8*)&smem[16384 + (mc & 1) * 4096];
        __builtin_amdgcn_s_setprio(1);
        #pragma unroll
        for (int og = 0; og < 8; ++og)
            O[og] = mfma16h(pa, VW8[og * 64 + l], O[og]);
        __builtin_amdgcn_s_setprio(0);

        // K(mc+1) landed (8 oldest of this iter's 10); VW(mc+1) may fly on
        asm volatile("s_waitcnt vmcnt(2)" ::: "memory");
        RAW_BARRIER();                        // barrier B
    }

    // epilogue: normalize + BN + ReLU, direct f32x4 store
    float inv[4];
    #pragma unroll
    for (int r = 0; r < 4; ++r) inv[r] = 1.f / lrow[r];
    int nb = ng * 16 + (l >> 4) * 4;
    #pragma unroll
    for (int og = 0; og < 8; ++og) {
        int o = og * 16 + (l & 15);
        float sc = sf[o], tb = tf[o];
        f32x4 res;
        #pragma unroll
        for (int r = 0; r < 4; ++r)
            res[r] = fmaxf(fmaf(O[og][r] * inv[r], sc, tb), 0.f);
        *(f32x4*)(out + ((size_t)b * COUT + o) * N_ + nb) = res;
    }
}

// ---------------------------------------------------------------------------
extern "C" void kernel_launch(void* const* d_in, const int* in_sizes, int n_in,
                              void* d_out, int out_size, void* d_ws, size_t ws_size,
                              hipStream_t stream)
{
    const float* x   = (const float*)d_in[0];
    const float* Wq  = (const float*)d_in[1];
    const float* Wk  = (const float*)d_in[2];
    const float* Wv  = (const float*)d_in[3];
    const float* Wf  = (const float*)d_in[4];
    const float* bnq = (const float*)d_in[5];
    const float* bnk = (const float*)d_in[6];
    const float* bnv = (const float*)d_in[7];
    const float* bnf = (const float*)d_in[8];
    float* out = (float*)d_out;

    const size_t NBUF = (size_t)B_ * N_ * C_;   // 8,388,608 u16 per buffer
    u16* qh  = (u16*)d_ws;
    u16* ql  = qh + NBUF;
    u16* kh  = ql + NBUF;
    u16* kl  = kh + NBUF;
    u16* vt  = kl + NBUF;
    u16* vwb = vt + NBUF;               // 16*2048*128 = 4,194,304 u16
    u16* wfh = vwb + 4194304;
    u16* wfl = wfh + 32768;
    u16* wAh = wfl + 32768;             // 3*16*5*64*8 = 122880 u16
    u16* wAl = wAh + 122880;
    float* sqkv = (float*)(wAl + 122880);
    float* tqkv = sqkv + 768;
    float* sf   = tqkv + 768;
    float* tf   = sf + 128;

    w_prep<<<dim3(76), dim3(256), 0, stream>>>(Wq, Wk, Wv, Wf, bnq, bnk, bnv, bnf,
                                               wAh, wAl, wfh, wfl, sqkv, tqkv, sf, tf);
    qkv_proj<<<dim3(1536), dim3(256), 0, stream>>>(x, wAh, wAl, sqkv, tqkv,
                                                   qh, ql, kh, kl, vt);
    vw_proj<<<dim3(256), dim3(256), 0, stream>>>(vt, wfh, wfl, vwb);
    attn_fwd<<<dim3(512), dim3(256), 0, stream>>>(qh, ql, kh, kl, vwb,
                                                  sf, tf, out);
}

// Round 8
// 190.210 us; speedup vs baseline: 1.2783x; 1.2783x over previous
//
#include <hip/hip_runtime.h>

typedef __attribute__((ext_vector_type(4))) float f32x4;
typedef __attribute__((ext_vector_type(16))) float f32x16;
typedef __attribute__((ext_vector_type(8))) short short8;
typedef __attribute__((ext_vector_type(4))) unsigned short us4;
typedef unsigned short u16;
typedef unsigned int u32;
typedef _Float16 f16;
typedef __attribute__((ext_vector_type(8))) f16 f16x8;
typedef __attribute__((ext_vector_type(2))) __fp16 fp16x2;

#define B_   16
#define N_   2048
#define C_   256
#define CIN  131
#define COUT 128
#define L2E  1.44269504088896f

__device__ __forceinline__ u16 f2bf(float x) {
    u32 u = __float_as_uint(x);
    u32 r = (u + 0x7fffu + ((u >> 16) & 1u)) >> 16;
    return (u16)r;
}
__device__ __forceinline__ float bf2f(u16 h) {
    return __uint_as_float(((u32)h) << 16);
}
__device__ __forceinline__ u16 f2h(float x) {
    union { f16 h; u16 u; } c; c.h = (f16)x; return c.u;
}

__device__ __forceinline__ f32x4 mfma16(short8 a, short8 b, f32x4 c) {
    return __builtin_amdgcn_mfma_f32_16x16x32_bf16(a, b, c, 0, 0, 0);
}
__device__ __forceinline__ f32x4 mfma16h(f16x8 a, f16x8 b, f32x4 c) {
    return __builtin_amdgcn_mfma_f32_16x16x32_f16(a, b, c, 0, 0, 0);
}
__device__ __forceinline__ f32x16 mfma32(short8 a, short8 b, f32x16 c) {
    return __builtin_amdgcn_mfma_f32_32x32x16_bf16(a, b, c, 0, 0, 0);
}
__device__ __forceinline__ f32x16 mfma32h(f16x8 a, f16x8 b, f32x16 c) {
    return __builtin_amdgcn_mfma_f32_32x32x16_f16(a, b, c, 0, 0, 0);
}
__device__ __forceinline__ f32x16 z16() {
    f32x16 v;
    #pragma unroll
    for (int i = 0; i < 16; ++i) v[i] = 0.f;
    return v;
}
__device__ __forceinline__ u32 pkrtz(float a, float b) {
    fp16x2 r = __builtin_amdgcn_cvt_pkrtz(a, b);
    union { fp16x2 v; u32 u; } c; c.v = r; return c.u;
}

typedef __attribute__((address_space(1))) const unsigned int gu32;
typedef __attribute__((address_space(3))) unsigned int lu32;
__device__ __forceinline__ void gl_lds16(const u16* g, u16* l) {
    __builtin_amdgcn_global_load_lds((gu32*)g, (lu32*)l, 16, 0, 0);
}

#define RAW_BARRIER() do { asm volatile("" ::: "memory"); \
    __builtin_amdgcn_s_barrier(); \
    asm volatile("" ::: "memory"); } while (0)

// ---------------------------------------------------------------------------
// Kernel 1: weight prep (unchanged).
// ---------------------------------------------------------------------------
__global__ __launch_bounds__(256) void w_prep(
    const float* __restrict__ Wq, const float* __restrict__ Wk,
    const float* __restrict__ Wv, const float* __restrict__ Wf,
    const float* __restrict__ bnq, const float* __restrict__ bnk,
    const float* __restrict__ bnv, const float* __restrict__ bnf,
    u16* __restrict__ wAh, u16* __restrict__ wAl,
    u16* __restrict__ wfh, u16* __restrict__ wfl,
    float* __restrict__ sqkv, float* __restrict__ tqkv,
    float* __restrict__ sf, float* __restrict__ tf)
{
    int t = threadIdx.x, l = t & 63;
    int g = blockIdx.x * 4 + (t >> 6);
    if (g < 240) {
        int m = g / 80, rem = g % 80, og = rem / 5, cc = rem % 5;
        const float* W = (m == 0) ? Wq : (m == 1) ? Wk : Wv;
        int o = og * 16 + (l & 15);
        size_t base = ((size_t)g * 64 + l) * 8;
        #pragma unroll
        for (int j = 0; j < 8; ++j) {
            int k = cc * 32 + (l >> 4) * 8 + j;
            float f = (k < CIN) ? W[o * CIN + k] : 0.f;
            u16 h = f2bf(f);
            wAh[base + j] = h;
            wAl[base + j] = f2bf(f - bf2f(h));
        }
    } else if (g < 304) {
        int u = g - 240;
        int o = (u >> 3) * 16 + (l & 15);
        int c0 = (u & 7) * 32 + (l >> 4) * 8;
        size_t base = ((size_t)u * 64 + l) * 8;
        #pragma unroll
        for (int j = 0; j < 8; ++j) {
            float f = Wf[o * 256 + c0 + j];
            u16 h = f2h(f);
            wfh[base + j] = h;
            union { f16 hh; u16 uu; } c; c.uu = h;
            wfl[base + j] = f2h(f - (float)c.hh);
        }
    }
    if (blockIdx.x == 0) {
        if (t < 256) {
            #pragma unroll
            for (int m = 0; m < 3; ++m) {
                const float* bn = (m == 0) ? bnq : (m == 1) ? bnk : bnv;
                float s = bn[t] * rsqrtf(bn[768 + t] + 1e-5f);
                sqkv[m * 256 + t] = s;
                tqkv[m * 256 + t] = bn[256 + t] - bn[512 + t] * s;
            }
        }
        if (t < 128) {
            float s = bnf[t] * rsqrtf(bnf[384 + t] + 1e-5f);
            sf[t] = s;
            tf[t] = bnf[128 + t] - bnf[256 + t] * s;
        }
    }
}

// ---------------------------------------------------------------------------
// Kernel 2: QKV projection via MFMA hi/lo bf16.
// Q/K stored as 32x32x16 frags: buf[b][t=n>>5][cc=c>>4][lane][j]
//   lane = ((c>>3)&1)*32 + (n&31), j = c&7.
// V unchanged (16x16 A-frag layout for vw_proj).
// ---------------------------------------------------------------------------
__global__ __launch_bounds__(256) void qkv_proj(
    const float* __restrict__ x,
    const u16* __restrict__ wAh, const u16* __restrict__ wAl,
    const float* __restrict__ sqkv, const float* __restrict__ tqkv,
    u16* __restrict__ qh, u16* __restrict__ ql,
    u16* __restrict__ kh, u16* __restrict__ kl, u16* __restrict__ vt)
{
    __shared__ __align__(16) float xs[64][164];

    int bid = blockIdx.x;
    int m  = bid >> 9;
    int r9 = bid & 511;
    int b = r9 >> 5, nt = r9 & 31;
    int t = threadIdx.x;
    int w = t >> 6, l = t & 63;
    int n0 = nt * 64;

    {
        int nb = (t & 15) * 4;
        for (int k = (t >> 4); k < CIN; k += 16) {
            f32x4 v = *(const f32x4*)(x + ((size_t)b * CIN + k) * N_ + n0 + nb);
            xs[nb + 0][k] = v[0]; xs[nb + 1][k] = v[1];
            xs[nb + 2][k] = v[2]; xs[nb + 3][k] = v[3];
        }
        for (int idx = t; idx < 64 * 29; idx += 256) {
            int n = idx / 29, k = CIN + idx % 29;
            xs[n][k] = 0.f;
        }
    }
    __syncthreads();

    f32x4 acc[4][4];
    #pragma unroll
    for (int og = 0; og < 4; ++og)
        #pragma unroll
        for (int njg = 0; njg < 4; ++njg) acc[og][njg] = (f32x4){0.f, 0.f, 0.f, 0.f};

    for (int cc = 0; cc < 5; ++cc) {
        short8 xbh[4], xbl[4];
        #pragma unroll
        for (int njg = 0; njg < 4; ++njg) {
            int n = njg * 16 + (l & 15);
            int k0 = cc * 32 + (l >> 4) * 8;
            f32x4 u0 = *(const f32x4*)&xs[n][k0];
            f32x4 u1 = *(const f32x4*)&xs[n][k0 + 4];
            u16 hh[8], ll[8];
            #pragma unroll
            for (int jj = 0; jj < 4; ++jj) {
                hh[jj] = f2bf(u0[jj]);     ll[jj] = f2bf(u0[jj] - bf2f(hh[jj]));
                hh[4 + jj] = f2bf(u1[jj]); ll[4 + jj] = f2bf(u1[jj] - bf2f(hh[4 + jj]));
            }
            short8 vh_, vl_;
            #pragma unroll
            for (int jj = 0; jj < 8; ++jj) { vh_[jj] = (short)hh[jj]; vl_[jj] = (short)ll[jj]; }
            xbh[njg] = vh_; xbl[njg] = vl_;
        }
        #pragma unroll
        for (int og = 0; og < 4; ++og) {
            size_t base = (((size_t)(m * 16 + w * 4 + og) * 5 + cc) * 64 + l) * 8;
            short8 ah  = *(const short8*)(wAh + base);
            short8 al4 = *(const short8*)(wAl + base);
            #pragma unroll
            for (int njg = 0; njg < 4; ++njg) {
                acc[og][njg] = mfma16(ah,  xbh[njg], acc[og][njg]);
                acc[og][njg] = mfma16(ah,  xbl[njg], acc[og][njg]);
                acc[og][njg] = mfma16(al4, xbh[njg], acc[og][njg]);
            }
        }
    }

    #pragma unroll
    for (int og = 0; og < 4; ++og) {
        int cb = (w * 4 + og) * 16 + (l >> 4) * 4;
        f32x4 sv = *(const f32x4*)(sqkv + m * 256 + cb);
        f32x4 tv = *(const f32x4*)(tqkv + m * 256 + cb);
        #pragma unroll
        for (int njg = 0; njg < 4; ++njg) {
            int n = n0 + njg * 16 + (l & 15);
            float z[4];
            #pragma unroll
            for (int r = 0; r < 4; ++r)
                z[r] = fmaxf(fmaf(acc[og][njg][r], sv[r], tv[r]), 0.f);
            if (m < 2) {
                // 32x32x16 frag store: tile = n>>5, cc' = cb>>4,
                // lane = ((cb>>3)&1)*32 + (n&31), j0 = ((cb>>2)&1)*4
                size_t base = ((((size_t)b * 64 + (n >> 5)) * 16 + (cb >> 4)) * 64
                               + ((cb >> 3) & 1) * 32 + (n & 31)) * 8 + ((cb >> 2) & 1) * 4;
                u16 h0 = f2bf(z[0]), h1 = f2bf(z[1]), h2 = f2bf(z[2]), h3 = f2bf(z[3]);
                us4 hi4 = { h0, h1, h2, h3 };
                us4 lo4 = { f2bf(z[0] - bf2f(h0)), f2bf(z[1] - bf2f(h1)),
                            f2bf(z[2] - bf2f(h2)), f2bf(z[3] - bf2f(h3)) };
                *(us4*)((m ? kh : qh) + base) = hi4;
                *(us4*)((m ? kl : ql) + base) = lo4;
            } else {
                size_t base = ((((size_t)b * 128 + (n >> 4)) * 8 + (cb >> 5)) * 64
                               + ((cb >> 3) & 3) * 16 + (n & 15)) * 8 + (cb & 7);
                us4 v0 = { f2h(z[0]), f2h(z[1]), f2h(z[2]), f2h(z[3]) };
                *(us4*)(vt + base) = v0;
            }
        }
    }
}

// ---------------------------------------------------------------------------
// Kernel 2b: VW = V^T · Wf (fp16).  Store: 32x32x16 B-frag layout:
// vw[b][mc][ot][mk][lane][j]: o = ot*32+(lane&31), m = mc*32+mk*16+8*(lane>>5)+j
// ---------------------------------------------------------------------------
__global__ __launch_bounds__(256) void vw_proj(
    const u16* __restrict__ vt,
    const u16* __restrict__ wfh, const u16* __restrict__ wfl,
    u16* __restrict__ vw)
{
    int bid = blockIdx.x;
    int b = bid >> 4, mt = bid & 15;
    int t = threadIdx.x, w = t >> 6, l = t & 63;

    f32x4 acc[2][8];
    #pragma unroll
    for (int oi = 0; oi < 2; ++oi)
        #pragma unroll
        for (int mg = 0; mg < 8; ++mg) acc[oi][mg] = (f32x4){0.f, 0.f, 0.f, 0.f};

    for (int cc = 0; cc < 8; ++cc) {
        f16x8 vtf[8];
        #pragma unroll
        for (int mg = 0; mg < 8; ++mg)
            vtf[mg] = *(const f16x8*)(vt + ((((size_t)b * 128 + mt * 8 + mg) * 8 + cc) * 64 + l) * 8);
        #pragma unroll
        for (int oi = 0; oi < 2; ++oi) {
            int og = w * 2 + oi;
            f16x8 bh = *(const f16x8*)(wfh + (((size_t)og * 8 + cc) * 64 + l) * 8);
            f16x8 bl = *(const f16x8*)(wfl + (((size_t)og * 8 + cc) * 64 + l) * 8);
            #pragma unroll
            for (int mg = 0; mg < 8; ++mg) {
                acc[oi][mg] = mfma16h(vtf[mg], bh, acc[oi][mg]);
                acc[oi][mg] = mfma16h(vtf[mg], bl, acc[oi][mg]);
            }
        }
    }

    #pragma unroll
    for (int oi = 0; oi < 2; ++oi) {
        int og = w * 2 + oi;
        int o = og * 16 + (l & 15);
        #pragma unroll
        for (int mg = 0; mg < 8; ++mg) {
            int mm0 = mt * 128 + mg * 16 + (l >> 4) * 4;   // r = 0..3 consecutive
            size_t idx = ((((size_t)b * 64 + (mm0 >> 5)) * 4 + (o >> 5)) * 2 + ((mm0 >> 4) & 1)) * 512
                         + (size_t)(((mm0 >> 3) & 1) * 32 + (o & 31)) * 8 + (mm0 & 7);
            us4 v = { f2h(acc[oi][mg][0]), f2h(acc[oi][mg][1]),
                      f2h(acc[oi][mg][2]), f2h(acc[oi][mg][3]) };
            *(us4*)(vw + idx) = v;
        }
    }
}

// ---------------------------------------------------------------------------
// Kernel 3: flash attention, 32-row waves, swapped 32x32x16 MFMA,
// in-register softmax, P->PV via cvt_pkrtz + shfl_xor(32) (no LDS bounce).
// Grid 256 = (b, qt); block 4 waves; wave w owns q-rows qt*128+w*32..+31.
// LDS (80.5KB u16 idx): K dbuf [2][16384] @0, VW dbuf [2][4096] @32768,
//                       als (4 waves x 32 f32) @40960.
// Single barrier per iter: stage(mc+1) at top, vmcnt(0)+s_barrier at bottom.
// ---------------------------------------------------------------------------
__global__ __launch_bounds__(256, 1) void attn_fwd(
    const u16* __restrict__ qh, const u16* __restrict__ ql,
    const u16* __restrict__ kh, const u16* __restrict__ kl,
    const u16* __restrict__ vw,
    const float* __restrict__ sf, const float* __restrict__ tf,
    float* __restrict__ out)
{
    __shared__ __align__(16) u16 smem[41216];

    int bid = blockIdx.x;
    int swz = (bid & 7) * 32 + (bid >> 3);   // XCD-chunked swizzle (bijective, 256)
    int b   = swz >> 4;
    int qt  = swz & 15;
    int tid = threadIdx.x;
    int w = tid >> 6, l = tid & 63;
    int h = l >> 5;
    int qw = qt * 4 + w;                     // global q-tile-32 index

    const u16* khb = kh + (size_t)b * 64 * 16 * 512;
    const u16* klb = kl + (size_t)b * 64 * 16 * 512;
    const u16* vwb = vw + (size_t)b * 64 * 8 * 512;

    auto stage = [&](int mc, int kbase, int vbase) {
        size_t ko = (size_t)mc * 16 * 512;
        #pragma unroll
        for (int i = 0; i < 8; ++i) {
            int g = w * 8 + i;               // 0..31: cc = g>>1, hl = g&1
            const u16* src = ((g & 1) ? klb : khb) + ko + (size_t)(g >> 1) * 512 + l * 8;
            gl_lds16(src, &smem[kbase + g * 512]);
        }
        size_t vo = (size_t)mc * 8 * 512;
        #pragma unroll
        for (int i = 0; i < 2; ++i) {
            int f = w * 2 + i;               // 0..7 = ot*2+mk
            gl_lds16(vwb + vo + (size_t)f * 512 + l * 8, &smem[vbase + f * 512]);
        }
    };

    // Q fragments (hi/lo), 16 c-chunks of 16
    short8 qfh[16], qfl[16];
    #pragma unroll
    for (int cc = 0; cc < 16; ++cc) {
        size_t o = (((size_t)b * 64 + qw) * 16 + cc) * 512 + (size_t)l * 8;
        qfh[cc] = *(const short8*)(qh + o);
        qfl[cc] = *(const short8*)(ql + o);
    }

    f32x16 O0 = z16(), O1 = z16(), O2 = z16(), O3 = z16();
    float mrow = -1e30f, lrow = 0.f;
    float* als = (float*)&smem[40960];
    int alb = w * 32;

    stage(0, 0, 32768);
    asm volatile("s_waitcnt vmcnt(0)" ::: "memory");
    __syncthreads();

    for (int mc = 0; mc < 64; ++mc) {
        int cur = mc & 1;
        int kbase = cur * 16384;
        int vbase = 32768 + cur * 4096;
        if (mc < 63) stage(mc + 1, (cur ^ 1) * 16384, 32768 + (cur ^ 1) * 4096);

        // ---- S = mfma(K, Q): D[m][q], col=lane&31=q, rows=16 regs ----
        const short8* KF = (const short8*)&smem[kbase];
        f32x16 sE = z16(), sO = z16();
        #pragma unroll
        for (int cc = 0; cc < 16; cc += 2) {
            short8 ke_h = KF[(cc * 2 + 0) * 64 + l];
            short8 ke_l = KF[(cc * 2 + 1) * 64 + l];
            short8 ko_h = KF[(cc * 2 + 2) * 64 + l];
            short8 ko_l = KF[(cc * 2 + 3) * 64 + l];
            sE = mfma32(ke_h, qfh[cc], sE);
            sO = mfma32(ko_h, qfh[cc + 1], sO);
            sE = mfma32(ke_h, qfl[cc], sE);
            sO = mfma32(ko_h, qfl[cc + 1], sO);
            sE = mfma32(ke_l, qfh[cc], sE);
            sO = mfma32(ko_l, qfh[cc + 1], sO);
        }
        float s[16];
        #pragma unroll
        for (int r = 0; r < 16; ++r) s[r] = sE[r] + sO[r];

        // ---- in-register online softmax (row = q = l&31, halves mirrored) ----
        float mx = s[0];
        #pragma unroll
        for (int r = 1; r < 16; ++r) mx = fmaxf(mx, s[r]);
        mx = fmaxf(mx, __shfl_xor(mx, 32));
        bool need = mx > mrow + 8.f;
        if (__any(need)) {
            float mn = fmaxf(mrow, mx);
            float al = exp2f((mrow - mn) * L2E);
            mrow = mn;
            lrow *= al;
            als[alb + (l & 31)] = al;
            asm volatile("s_waitcnt lgkmcnt(0)" ::: "memory");
            f32x4 aq[4];
            #pragma unroll
            for (int g = 0; g < 4; ++g)
                aq[g] = *(const f32x4*)&als[alb + 8 * g + 4 * h];
            #pragma unroll
            for (int r = 0; r < 16; ++r) {
                float f = aq[r >> 2][r & 3];
                O0[r] *= f; O1[r] *= f; O2[r] *= f; O3[r] *= f;
            }
        }
        float p[16], sum = 0.f;
        #pragma unroll
        for (int r = 0; r < 16; ++r) {
            p[r] = exp2f((s[r] - mrow) * L2E);
            sum += p[r];
        }
        sum += __shfl_xor(sum, 32);
        lrow += sum;

        // ---- pack P to fp16 A-frags: pa[ks][j] = P[q][m=16ks+8h+j] ----
        // own L quad = p[8ks+0..3], own H quad = p[8ks+4..7]
        // half0 frag = [own L | partner L]; half1 frag = [partner H | own H]
        f16x8 pa0, pa1;
        #pragma unroll
        for (int ks = 0; ks < 2; ++ks) {
            u32 L0 = pkrtz(p[8 * ks + 0], p[8 * ks + 1]);
            u32 L1 = pkrtz(p[8 * ks + 2], p[8 * ks + 3]);
            u32 H0 = pkrtz(p[8 * ks + 4], p[8 * ks + 5]);
            u32 H1 = pkrtz(p[8 * ks + 6], p[8 * ks + 7]);
            u32 pL0 = (u32)__shfl_xor((int)L0, 32);
            u32 pL1 = (u32)__shfl_xor((int)L1, 32);
            u32 pH0 = (u32)__shfl_xor((int)H0, 32);
            u32 pH1 = (u32)__shfl_xor((int)H1, 32);
            union { u32 w[4]; f16x8 v; } u;
            u.w[0] = h ? pH0 : L0;
            u.w[1] = h ? pH1 : L1;
            u.w[2] = h ? H0 : pL0;
            u.w[3] = h ? H1 : pL1;
            if (ks == 0) pa0 = u.v; else pa1 = u.v;
        }

        // ---- O += P · VW (fp16, 8 MFMA 32x32x16) ----
        const f16x8* VWF = (const f16x8*)&smem[vbase];
        O0 = mfma32h(pa0, VWF[0 * 64 + l], O0);
        O1 = mfma32h(pa0, VWF[2 * 64 + l], O1);
        O2 = mfma32h(pa0, VWF[4 * 64 + l], O2);
        O3 = mfma32h(pa0, VWF[6 * 64 + l], O3);
        O0 = mfma32h(pa1, VWF[1 * 64 + l], O0);
        O1 = mfma32h(pa1, VWF[3 * 64 + l], O1);
        O2 = mfma32h(pa1, VWF[5 * 64 + l], O2);
        O3 = mfma32h(pa1, VWF[7 * 64 + l], O3);

        asm volatile("s_waitcnt vmcnt(0)" ::: "memory");
        RAW_BARRIER();
    }

    // ---- epilogue: normalize + BN + ReLU ----
    als[alb + (l & 31)] = 1.f / lrow;
    asm volatile("s_waitcnt lgkmcnt(0)" ::: "memory");
    f32x4 iv[4];
    #pragma unroll
    for (int g = 0; g < 4; ++g)
        iv[g] = *(const f32x4*)&als[alb + 8 * g + 4 * h];

    int n0 = qt * 128 + w * 32;
    #pragma unroll
    for (int ot = 0; ot < 4; ++ot) {
        const f32x16& Ov = (ot == 0) ? O0 : (ot == 1) ? O1 : (ot == 2) ? O2 : O3;
        int o = ot * 32 + (l & 31);
        float sc = sf[o], tb = tf[o];
        #pragma unroll
        for (int g = 0; g < 4; ++g) {
            f32x4 res;
            #pragma unroll
            for (int rr = 0; rr < 4; ++rr)
                res[rr] = fmaxf(fmaf(Ov[g * 4 + rr] * iv[g][rr], sc, tb), 0.f);
            *(f32x4*)(out + ((size_t)b * COUT + o) * N_ + n0 + 8 * g + 4 * h) = res;
        }
    }
}

// ---------------------------------------------------------------------------
extern "C" void kernel_launch(void* const* d_in, const int* in_sizes, int n_in,
                              void* d_out, int out_size, void* d_ws, size_t ws_size,
                              hipStream_t stream)
{
    const float* x   = (const float*)d_in[0];
    const float* Wq  = (const float*)d_in[1];
    const float* Wk  = (const float*)d_in[2];
    const float* Wv  = (const float*)d_in[3];
    const float* Wf  = (const float*)d_in[4];
    const float* bnq = (const float*)d_in[5];
    const float* bnk = (const float*)d_in[6];
    const float* bnv = (const float*)d_in[7];
    const float* bnf = (const float*)d_in[8];
    float* out = (float*)d_out;

    const size_t NBUF = (size_t)B_ * N_ * C_;   // 8,388,608 u16 per buffer
    u16* qh  = (u16*)d_ws;
    u16* ql  = qh + NBUF;
    u16* kh  = ql + NBUF;
    u16* kl  = kh + NBUF;
    u16* vt  = kl + NBUF;
    u16* vwb = vt + NBUF;               // 16*64*8*512 = 4,194,304 u16
    u16* wfh = vwb + 4194304;
    u16* wfl = wfh + 32768;
    u16* wAh = wfl + 32768;             // 3*16*5*64*8 = 122880 u16
    u16* wAl = wAh + 122880;
    float* sqkv = (float*)(wAl + 122880);
    float* tqkv = sqkv + 768;
    float* sf   = tqkv + 768;
    float* tf   = sf + 128;

    w_prep<<<dim3(76), dim3(256), 0, stream>>>(Wq, Wk, Wv, Wf, bnq, bnk, bnv, bnf,
                                               wAh, wAl, wfh, wfl, sqkv, tqkv, sf, tf);
    qkv_proj<<<dim3(1536), dim3(256), 0, stream>>>(x, wAh, wAl, sqkv, tqkv,
                                                   qh, ql, kh, kl, vt);
    vw_proj<<<dim3(256), dim3(256), 0, stream>>>(vt, wfh, wfl, vwb);
    attn_fwd<<<dim3(256), dim3(256), 0, stream>>>(qh, ql, kh, kl, vwb,
                                                  sf, tf, out);
}